// Round 4
// baseline (364.492 us; speedup 1.0000x reference)
//
#include <hip/hip_runtime.h>
#include <hip/hip_bf16.h>
#include <math.h>

// Problem dims (fixed by reference)
#define BB 4
#define TT 1024
#define DD 1024
#define HPS 4          // heads per scale
#define C0 21
#define C1 41
#define N0 (HPS * C0)  // 84
#define N1 (HPS * C1)  // 164
#define NL 256         // padded combined logits width (84 + 164 = 248 -> 256)
#define BT (BB * TT)   // 4096
#define KSPLIT 2       // split-K for logits phase
#define NBLK 512       // persistent grid size (2 blocks/CU, all co-resident)
#define TB2 32         // t-tile for window phase
#define HALO 20
#define HB2 (TB2 + 2 * HALO)  // 72 rows staged

typedef unsigned int uint;
typedef __bf16 bf16x8 __attribute__((ext_vector_type(8)));
typedef float f32x4 __attribute__((ext_vector_type(4)));

__device__ __forceinline__ ushort f2bf(float f) {
    union { float f; uint u; } v; v.f = f;
    uint u = v.u;
    uint r = (u + 0x7FFFu + ((u >> 16) & 1u)) >> 16;
    return (ushort)r;
}
__device__ __forceinline__ float bf2f(ushort s) {
    union { uint u; float f; } v; v.u = ((uint)s) << 16;
    return v.f;
}

// ---------------- fused conversion kernel (also zeroes the grid barrier) ----------------
#define RQ  4096
#define R1  (RQ + 2048)
#define R2  (R1 + 1024)
#define R3  (R2 + 96)
#define R4  (R3 + 192)

__device__ __forceinline__ void transpose_tile(
    const float* __restrict__ in, ushort* __restrict__ out,
    int K, int Nin, int n_base, int Npad, int nx, int ky, int tid)
{
    __shared__ float tile[32][33];
    const int tx = tid & 31;
    const int ty = tid >> 5;   // 0..7
    const int n0 = nx * 32;
    const int k0 = ky * 32;
    #pragma unroll
    for (int i = 0; i < 4; i++) {
        int k = k0 + ty + i * 8;
        int n = n0 + tx;
        float v = (k < K && n < Nin) ? in[(size_t)k * Nin + n] : 0.0f;
        tile[ty + i * 8][tx] = v;
    }
    __syncthreads();
    #pragma unroll
    for (int i = 0; i < 4; i++) {
        int n = n0 + ty + i * 8;
        int k = k0 + tx;
        if (n < Npad && k < K)
            out[(size_t)(n_base + n) * K + k] = f2bf(tile[tx][ty + i * 8]);
    }
}

__global__ __launch_bounds__(256) void convert_all(
    const float* __restrict__ query, ushort* __restrict__ query_bf,
    const float* __restrict__ W_qv,  ushort* __restrict__ WqvT,
    const float* __restrict__ W_out, ushort* __restrict__ WoutT,
    const float* __restrict__ W2_0, const float* __restrict__ W2_1,
    ushort* __restrict__ W2T, uint* __restrict__ bar)
{
    const int blk = blockIdx.x;
    const int tid = threadIdx.x;
    if (blk == 0 && tid == 0) *bar = 0u;   // re-arm grid barrier (ws is poisoned)
    if (blk < RQ) {
        int i = blk * 1024 + tid * 4;
        float4 v = *(const float4*)(query + i);
        ushort4 o;
        o.x = f2bf(v.x); o.y = f2bf(v.y); o.z = f2bf(v.z); o.w = f2bf(v.w);
        *(ushort4*)(query_bf + i) = o;
    } else if (blk < R1) {
        int idx = blk - RQ;                // 64 x 32
        transpose_tile(W_qv, WqvT, DD, 2 * DD, 0, 2 * DD, idx & 63, idx >> 6, tid);
    } else if (blk < R2) {
        int idx = blk - R1;                // 32 x 32
        transpose_tile(W_out, WoutT, DD, DD, 0, DD, idx & 31, idx >> 5, tid);
    } else if (blk < R3) {
        int idx = blk - R2;                // 3 x 32
        transpose_tile(W2_0, W2T, DD, N0, 0, N0, idx % 3, idx / 3, tid);
    } else {
        int idx = blk - R3;                // 6 x 32
        transpose_tile(W2_1, W2T, DD, N1, N0, NL - N0, idx % 6, idx / 6, tid);
    }
}

// ---------------- software grid barrier (all NBLK blocks co-resident) ----------------
// Monotonic-generation counter: each use adds NBLK; no reset needed between uses.
// Agent-scope acq_rel RMW + acquire spin + __threadfence gives cross-XCD visibility
// (per-XCD L2s are not coherent; fences emit the writeback/invalidate ops).
__device__ __forceinline__ void grid_barrier(uint* bar) {
    __syncthreads();
    if (threadIdx.x == 0) {
        __threadfence();   // release this block's plain global stores (agent scope)
        uint arrive = __hip_atomic_fetch_add(bar, 1u, __ATOMIC_ACQ_REL,
                                             __HIP_MEMORY_SCOPE_AGENT);
        uint target = (arrive / NBLK + 1u) * (uint)NBLK;
        while (__hip_atomic_load(bar, __ATOMIC_ACQUIRE,
                                 __HIP_MEMORY_SCOPE_AGENT) < target)
            __builtin_amdgcn_s_sleep(2);
        __threadfence();   // acquire: invalidate stale cached lines before next phase
    }
    __syncthreads();
}

// ---------------- generic bf16 MFMA GEMM phase (device function) ----------------
// Tile MT x NT (MT,NT in {64,128}), BK=64, double-buffered LDS, 4 waves in 2x2.
// A: [M][K] bf16 row-major. Bt: [N][K] bf16 row-major. K,klen multiples of 64.
// LDS layout per buffer: [row][chunk 0..7][8 ushort]; slot (r,c) holds global
// chunk c^(r&7) (XOR swizzle). Staging lane l covers row base+(l>>3), slot l&7
// -> global chunk (l&7)^(l>>3) (all row bases are multiples of 8).
// mode 0: Cf[row*ldc+col] = acc
// mode 2: col<DD -> Cb[row*DD+col] = bf16(relu(acc)); else Cv[row*DD+col-DD] = bf16(acc)
template<int MT, int NT>
__device__ __forceinline__ void gemm_phase(
    ushort* lds,
    const ushort* __restrict__ A, const ushort* __restrict__ Bt,
    int K, int klen, int kbase, int row0, int col0,
    float* __restrict__ Cf, ushort* __restrict__ Cb, ushort* __restrict__ Cv,
    int mode, int ldc)
{
    constexpr int MR = MT / 32;   // acc rows (16-frags per wave, M dir)
    constexpr int NR = NT / 32;   // acc cols
    ushort* As = lds;                       // [2][MT*64]
    ushort* Bs = lds + 2 * MT * 64;         // [2][NT*64]

    const int tid = threadIdx.x;
    const int wv  = tid >> 6;
    const int ln  = tid & 63;
    const int wr = (wv >> 1) * (MT / 2);
    const int wc = (wv & 1) * (NT / 2);
    const int l15 = ln & 15;
    const int lq  = ln >> 4;

    f32x4 acc[MR][NR];
    #pragma unroll
    for (int i = 0; i < MR; i++)
        #pragma unroll
        for (int j = 0; j < NR; j++)
            acc[i][j] = (f32x4){0.f, 0.f, 0.f, 0.f};

    const int rsub = ln >> 3;               // 0..7
    const int cg   = (ln & 7) ^ rsub;       // swizzled global chunk
    const ushort* gA = A  + (size_t)(row0 + wv * (MT / 4) + rsub) * K + kbase + cg * 8;
    const ushort* gB = Bt + (size_t)(col0 + wv * (NT / 4) + rsub) * K + kbase + cg * 8;
    const int fx = l15 & 7;
    const int nt = klen / 64;

    auto STAGE = [&](int buf, int kk) {
        #pragma unroll
        for (int i = 0; i < MT / 32; i++) {
            __builtin_amdgcn_global_load_lds(
                (const __attribute__((address_space(1))) void*)(gA + (size_t)i * 8 * K + kk),
                (__attribute__((address_space(3))) void*)(&As[buf * MT * 64 + (wv * (MT / 4) + i * 8) * 64]),
                16, 0, 0);
        }
        #pragma unroll
        for (int i = 0; i < NT / 32; i++) {
            __builtin_amdgcn_global_load_lds(
                (const __attribute__((address_space(1))) void*)(gB + (size_t)i * 8 * K + kk),
                (__attribute__((address_space(3))) void*)(&Bs[buf * NT * 64 + (wv * (NT / 4) + i * 8) * 64]),
                16, 0, 0);
        }
    };

    auto COMPUTE = [&](int buf) {
        #pragma unroll
        for (int s = 0; s < 2; s++) {
            const int ca = ((s * 4 + lq) ^ fx) * 8;
            bf16x8 af[MR], bfr[NR];
            #pragma unroll
            for (int mi = 0; mi < MR; mi++)
                af[mi] = *(const bf16x8*)&As[buf * MT * 64 + (wr + mi * 16 + l15) * 64 + ca];
            #pragma unroll
            for (int ni = 0; ni < NR; ni++)
                bfr[ni] = *(const bf16x8*)&Bs[buf * NT * 64 + (wc + ni * 16 + l15) * 64 + ca];
            #pragma unroll
            for (int mi = 0; mi < MR; mi++)
                #pragma unroll
                for (int ni = 0; ni < NR; ni++)
                    acc[mi][ni] = __builtin_amdgcn_mfma_f32_16x16x32_bf16(
                        af[mi], bfr[ni], acc[mi][ni], 0, 0, 0);
        }
    };

    int cur = 0;
    STAGE(0, 0);
    __syncthreads();
    for (int t = 0; t < nt; ++t) {
        const bool more = (t + 1 < nt);
        if (more) STAGE(cur ^ 1, (t + 1) * 64);
        COMPUTE(cur);
        if (more) __syncthreads();
        cur ^= 1;
    }
    __syncthreads();   // all LDS reads done before caller reuses LDS

    // Epilogue. D layout: col = lane&15, row = (lane>>4)*4 + reg.
    #pragma unroll
    for (int mi = 0; mi < MR; mi++) {
        #pragma unroll
        for (int ni = 0; ni < NR; ni++) {
            #pragma unroll
            for (int r = 0; r < 4; r++) {
                int row = row0 + wr + mi * 16 + lq * 4 + r;
                int col = col0 + wc + ni * 16 + l15;
                float v = acc[mi][ni][r];
                if (mode == 0) {
                    Cf[(size_t)row * ldc + col] = v;
                } else {
                    if (col < DD) Cb[(size_t)row * DD + col] = f2bf(fmaxf(v, 0.0f));
                    else          Cv[(size_t)row * DD + (col - DD)] = f2bf(v);
                }
            }
        }
    }
}

// ---------------- window phase: block = (b, t-tile of 32, head) ----------------
__device__ __forceinline__ void attn_phase(
    char* smem, const ushort* __restrict__ v, const float* __restrict__ Lp,
    const float* __restrict__ scale_w, ushort* __restrict__ x, int blk)
{
    ushort (*vs)[256] = (ushort (*)[256])smem;                 // 72x256 bf16 = 36,864 B
    float  (*cw)[42]  = (float  (*)[42])(smem + HB2 * 256 * 2); // 32x42 f32 = 5,376 B

    const int h  = blk & 3;
    const int tt = (blk >> 2) & 31;
    const int b  = blk >> 7;
    const int t0 = tt * TB2;
    const int tid = threadIdx.x;
    const size_t PS = (size_t)BT * NL;

    const ushort* vb = v + (size_t)b * TT * DD + h * 256;
    #pragma unroll
    for (int i = 0; i < 9; i++) {          // 72 rows x 32 uint4 = 2304 slots
        int c = i * 256 + tid;
        int r = c >> 5;
        int cir = c & 31;
        int t = t0 - HALO + r;
        uint4 val = make_uint4(0, 0, 0, 0);
        if (t >= 0 && t < TT)
            val = *(const uint4*)(vb + (size_t)t * DD + cir * 8);
        *(uint4*)(&vs[r][cir * 8]) = val;
    }

    if (tid < TB2) {
        const int bt = b * TT + t0 + tid;
        const float* Lb = Lp + (size_t)bt * NL;

        float s0 = scale_w[0], s1 = scale_w[1];
        float mm = fmaxf(s0, s1);
        float e0 = __expf(s0 - mm), e1 = __expf(s1 - mm);
        float inv01 = 1.0f / (e0 + e1);
        float sw0 = e0 * inv01, sw1 = e1 * inv01;

        float w0[C0], w1[C1];
        {
            const int off = h * C0;
            float m = -1e30f;
            #pragma unroll
            for (int j = 0; j < C0; j++) {
                float sacc = 0.0f;
                #pragma unroll
                for (int z = 0; z < KSPLIT; z++) sacc += Lb[(size_t)z * PS + off + j];
                w0[j] = sacc;
                m = fmaxf(m, w0[j]);
            }
            float s = 0.0f;
            #pragma unroll
            for (int j = 0; j < C0; j++) { w0[j] = __expf(w0[j] - m); s += w0[j]; }
            float inv = sw0 / s;
            #pragma unroll
            for (int j = 0; j < C0; j++) w0[j] *= inv;
        }
        {
            const int off = N0 + h * C1;
            float m = -1e30f;
            #pragma unroll
            for (int j = 0; j < C1; j++) {
                float sacc = 0.0f;
                #pragma unroll
                for (int z = 0; z < KSPLIT; z++) sacc += Lb[(size_t)z * PS + off + j];
                w1[j] = sacc;
                m = fmaxf(m, w1[j]);
            }
            float s = 0.0f;
            #pragma unroll
            for (int j = 0; j < C1; j++) { w1[j] = __expf(w1[j] - m); s += w1[j]; }
            float inv = sw1 / s;
            #pragma unroll
            for (int j = 0; j < C1; j++) w1[j] *= inv;
        }
        #pragma unroll
        for (int o = 0; o < C1; o++) {
            float w = w1[o];
            if (o >= 10 && o <= 30) w += w0[o - 10];
            cw[tid][o] = w;
        }
    }
    __syncthreads();

    const int tq = tid >> 6;
    const int dg = tid & 63;
    const int d  = dg * 4;

    for (int tloc = 0; tloc < 8; tloc++) {
        const int tp = tq * 8 + tloc;
        f32x4 acc = {0.f, 0.f, 0.f, 0.f};
        #pragma unroll
        for (int o = 0; o < C1; o++) {
            float w = cw[tp][o];
            ushort4 vv = *(const ushort4*)(&vs[tp + o][d]);
            acc[0] = fmaf(w, bf2f(vv.x), acc[0]);
            acc[1] = fmaf(w, bf2f(vv.y), acc[1]);
            acc[2] = fmaf(w, bf2f(vv.z), acc[2]);
            acc[3] = fmaf(w, bf2f(vv.w), acc[3]);
        }
        const int bt = b * TT + t0 + tp;
        ushort4 o4;
        o4.x = f2bf(acc[0]); o4.y = f2bf(acc[1]);
        o4.z = f2bf(acc[2]); o4.w = f2bf(acc[3]);
        *(ushort4*)(x + (size_t)bt * DD + h * 256 + d) = o4;
    }
    __syncthreads();   // LDS reads done before next phase reuses LDS
}

// ---------------- persistent fused kernel: qv -> logits -> window -> out ----------------
// 512 blocks (2/CU, 64 KB LDS each) stay resident; phases separated by software
// grid barriers. One dispatch = whole dependent chain (3 launch gaps removed,
// and the chain's true duration becomes directly visible in rocprof).
__global__ __launch_bounds__(256, 2) void mega(
    const ushort* __restrict__ query_bf, const ushort* __restrict__ WqvT,
    const ushort* __restrict__ W2T, const ushort* __restrict__ WoutT,
    ushort* __restrict__ reluq, ushort* __restrict__ vbuf,
    float* __restrict__ logitsP, ushort* __restrict__ xbuf,
    const float* __restrict__ scale_w, float* __restrict__ out,
    uint* __restrict__ bar)
{
    __shared__ __attribute__((aligned(16))) char smem[65536];
    ushort* lds = (ushort*)smem;
    const int blk = blockIdx.x;

    // Phase A: qv GEMM [4096,1024]x[1024,2048], 512 tiles of 128x128 (1 each)
    {
        const int bx = blk & 15;          // 16 N-tiles over 2048
        const int by = blk >> 4;          // 32 M-tiles over 4096
        gemm_phase<128, 128>(lds, query_bf, WqvT, DD, DD, 0,
                             by * 128, bx * 128,
                             nullptr, reluq, vbuf, 2, 0);
    }
    grid_barrier(bar);

    // Phase B: logits GEMM relu(q) x W2T, 64x64 tiles, split-K=2 -> 512 tiles
    {
        const int bz = blk & 1;
        const int bx = (blk >> 1) & 3;    // 4 N-tiles over 256
        const int by = blk >> 3;          // 64 M-tiles over 4096
        gemm_phase<64, 64>(lds, reluq, W2T, DD, DD / KSPLIT, bz * (DD / KSPLIT),
                           by * 64, bx * 64,
                           logitsP + (size_t)bz * BT * NL, nullptr, nullptr, 0, NL);
    }
    grid_barrier(bar);

    // Phase C: softmax + sliding window -> xbuf
    attn_phase(smem, vbuf, logitsP, scale_w, xbuf, blk);
    grid_barrier(bar);

    // Phase D: out GEMM x @ WoutT, 128x64 tiles -> 512 tiles (1 each)
    {
        const int bx = blk & 15;          // 16 N-tiles over 1024
        const int by = blk >> 4;          // 32 M-tiles over 4096
        gemm_phase<128, 64>(lds, xbuf, WoutT, DD, DD, 0,
                            by * 128, bx * 64,
                            out, nullptr, nullptr, 0, DD);
    }
}

// ---------------------------------- launch ----------------------------------
extern "C" void kernel_launch(void* const* d_in, const int* in_sizes, int n_in,
                              void* d_out, int out_size, void* d_ws, size_t ws_size,
                              hipStream_t stream)
{
    const float* query   = (const float*)d_in[0];
    const float* W_qv    = (const float*)d_in[3];
    const float* W2_0    = (const float*)d_in[4];
    const float* W2_1    = (const float*)d_in[5];
    const float* scale_w = (const float*)d_in[6];
    const float* W_out   = (const float*)d_in[7];
    float* out = (float*)d_out;

    // Workspace layout
    char* ws = (char*)d_ws;
    ushort* W2T      = (ushort*)ws;                 ws += (size_t)NL * DD * 2;          // 0.5 MB
    ushort* WoutT    = (ushort*)ws;                 ws += (size_t)DD * DD * 2;          // 2 MB
    ushort* query_bf = (ushort*)ws;                 ws += (size_t)BT * DD * 2;          // 8 MB
    ushort* WqvT     = (ushort*)ws;                 ws += (size_t)2 * DD * DD * 2;      // 4 MB
    ushort* reluq    = (ushort*)ws;                 ws += (size_t)BT * DD * 2;          // 8 MB
    ushort* vbuf     = (ushort*)ws;                 ws += (size_t)BT * DD * 2;          // 8 MB
    ushort* xbuf     = (ushort*)ws;                 ws += (size_t)BT * DD * 2;          // 8 MB
    float*  logitsP  = (float*)ws;                  ws += (size_t)KSPLIT * BT * NL * 4; // 8 MB
    uint*   bar      = (uint*)ws;                   ws += 4096;

    // 0) conversions + barrier re-arm
    convert_all<<<R4, 256, 0, stream>>>(query, query_bf, W_qv, WqvT,
                                        W_out, WoutT, W2_0, W2_1, W2T, bar);

    // 1) fused persistent chain: qv -> logits -> window -> out
    mega<<<NBLK, 256, 0, stream>>>(query_bf, WqvT, W2T, WoutT,
                                   reluq, vbuf, logitsP, xbuf,
                                   scale_w, out, bar);
}

// Round 5
// 323.498 us; speedup vs baseline: 1.1267x; 1.1267x over previous
//
#include <hip/hip_runtime.h>
#include <hip/hip_bf16.h>
#include <math.h>

// Problem dims (fixed by reference)
#define BB 4
#define TT 1024
#define DD 1024
#define HPS 4          // heads per scale
#define C0 21
#define C1 41
#define N0 (HPS * C0)  // 84
#define N1 (HPS * C1)  // 164
#define NL 256         // padded combined logits width (84 + 164 = 248 -> 256)
#define BT (BB * TT)   // 4096
#define KSPLIT 2       // split-K for logits phase
#define NBLK 512       // persistent grid size (2 blocks/CU, all co-resident)
#define TB2 32         // t-tile for window phase
#define HALO 20
#define HB2 (TB2 + 2 * HALO)  // 72 rows staged

typedef unsigned int uint;
typedef __bf16 bf16x8 __attribute__((ext_vector_type(8)));
typedef float f32x4 __attribute__((ext_vector_type(4)));

__device__ __forceinline__ ushort f2bf(float f) {
    union { float f; uint u; } v; v.f = f;
    uint u = v.u;
    uint r = (u + 0x7FFFu + ((u >> 16) & 1u)) >> 16;
    return (ushort)r;
}
__device__ __forceinline__ float bf2f(ushort s) {
    union { uint u; float f; } v; v.u = ((uint)s) << 16;
    return v.f;
}

// ---------------- fused conversion kernel (also zeroes the grid barrier) ----------------
#define RQ  4096
#define R1  (RQ + 2048)
#define R2  (R1 + 1024)
#define R3  (R2 + 96)
#define R4  (R3 + 192)

__device__ __forceinline__ void transpose_tile(
    const float* __restrict__ in, ushort* __restrict__ out,
    int K, int Nin, int n_base, int Npad, int nx, int ky, int tid)
{
    __shared__ float tile[32][33];
    const int tx = tid & 31;
    const int ty = tid >> 5;   // 0..7
    const int n0 = nx * 32;
    const int k0 = ky * 32;
    #pragma unroll
    for (int i = 0; i < 4; i++) {
        int k = k0 + ty + i * 8;
        int n = n0 + tx;
        float v = (k < K && n < Nin) ? in[(size_t)k * Nin + n] : 0.0f;
        tile[ty + i * 8][tx] = v;
    }
    __syncthreads();
    #pragma unroll
    for (int i = 0; i < 4; i++) {
        int n = n0 + ty + i * 8;
        int k = k0 + tx;
        if (n < Npad && k < K)
            out[(size_t)(n_base + n) * K + k] = f2bf(tile[tx][ty + i * 8]);
    }
}

__global__ __launch_bounds__(256) void convert_all(
    const float* __restrict__ query, ushort* __restrict__ query_bf,
    const float* __restrict__ W_qv,  ushort* __restrict__ WqvT,
    const float* __restrict__ W_out, ushort* __restrict__ WoutT,
    const float* __restrict__ W2_0, const float* __restrict__ W2_1,
    ushort* __restrict__ W2T, uint* __restrict__ bar)
{
    const int blk = blockIdx.x;
    const int tid = threadIdx.x;
    if (blk == 0 && tid == 0) *bar = 0u;   // re-arm grid barrier (ws is poisoned)
    if (blk < RQ) {
        int i = blk * 1024 + tid * 4;
        float4 v = *(const float4*)(query + i);
        ushort4 o;
        o.x = f2bf(v.x); o.y = f2bf(v.y); o.z = f2bf(v.z); o.w = f2bf(v.w);
        *(ushort4*)(query_bf + i) = o;
    } else if (blk < R1) {
        int idx = blk - RQ;                // 64 x 32
        transpose_tile(W_qv, WqvT, DD, 2 * DD, 0, 2 * DD, idx & 63, idx >> 6, tid);
    } else if (blk < R2) {
        int idx = blk - R1;                // 32 x 32
        transpose_tile(W_out, WoutT, DD, DD, 0, DD, idx & 31, idx >> 5, tid);
    } else if (blk < R3) {
        int idx = blk - R2;                // 3 x 32
        transpose_tile(W2_0, W2T, DD, N0, 0, N0, idx % 3, idx / 3, tid);
    } else {
        int idx = blk - R3;                // 6 x 32
        transpose_tile(W2_1, W2T, DD, N1, N0, NL - N0, idx % 6, idx / 6, tid);
    }
}

// ---------------- software grid barrier (all NBLK blocks co-resident) ----------------
// FIX vs R4: poll with RELAXED atomic loads (coherent for this address, but NO
// per-poll L2 invalidate — the R4 ACQUIRE-per-poll emitted a buffer_inv storm
// that evicted every block's working set and cost ~57 us/barrier). Ordering is
// provided by exactly ONE release fence before arrival and ONE acquire fence
// after the spin exits (fence-to-fence synchronization through the counter).
// Monotonic-generation counter: each use adds NBLK; no reset between uses.
__device__ __forceinline__ void grid_barrier(uint* bar) {
    __syncthreads();
    if (threadIdx.x == 0) {
        __threadfence();   // release: make this block's stores agent-visible
        uint arrive = __hip_atomic_fetch_add(bar, 1u, __ATOMIC_RELAXED,
                                             __HIP_MEMORY_SCOPE_AGENT);
        uint target = (arrive / NBLK + 1u) * (uint)NBLK;
        while (__hip_atomic_load(bar, __ATOMIC_RELAXED,
                                 __HIP_MEMORY_SCOPE_AGENT) < target)
            __builtin_amdgcn_s_sleep(8);   // ~512 cy backoff between polls
        __threadfence();   // acquire: one-time invalidate of stale cached lines
    }
    __syncthreads();
}

// XCD-chunked bijective tile remap (T1). Dispatch round-robins blk%8 across
// XCDs; this gives XCD x the contiguous logical-tile range [x*(n/8), ...).
// Requires n % 8 == 0 (all phase grids are 512). Correctness-neutral.
__device__ __forceinline__ int xcd_chunk(int blk, int nblk) {
    int q = nblk >> 3;
    return (blk & 7) * q + (blk >> 3);
}

// ---------------- generic bf16 MFMA GEMM phase (device function) ----------------
// Tile MT x NT (MT,NT in {64,128}), BK=64, double-buffered LDS, 4 waves in 2x2.
// A: [M][K] bf16 row-major. Bt: [N][K] bf16 row-major. K,klen multiples of 64.
// LDS layout per buffer: [row][chunk 0..7][8 ushort]; slot (r,c) holds global
// chunk c^(r&7) (XOR swizzle). Staging lane l covers row base+(l>>3), slot l&7
// -> global chunk (l&7)^(l>>3) (all row bases are multiples of 8).
// mode 0: Cf[row*ldc+col] = acc
// mode 2: col<DD -> Cb[row*DD+col] = bf16(relu(acc)); else Cv[row*DD+col-DD] = bf16(acc)
template<int MT, int NT>
__device__ __forceinline__ void gemm_phase(
    ushort* lds,
    const ushort* __restrict__ A, const ushort* __restrict__ Bt,
    int K, int klen, int kbase, int row0, int col0,
    float* __restrict__ Cf, ushort* __restrict__ Cb, ushort* __restrict__ Cv,
    int mode, int ldc)
{
    constexpr int MR = MT / 32;   // acc rows (16-frags per wave, M dir)
    constexpr int NR = NT / 32;   // acc cols
    ushort* As = lds;                       // [2][MT*64]
    ushort* Bs = lds + 2 * MT * 64;         // [2][NT*64]

    const int tid = threadIdx.x;
    const int wv  = tid >> 6;
    const int ln  = tid & 63;
    const int wr = (wv >> 1) * (MT / 2);
    const int wc = (wv & 1) * (NT / 2);
    const int l15 = ln & 15;
    const int lq  = ln >> 4;

    f32x4 acc[MR][NR];
    #pragma unroll
    for (int i = 0; i < MR; i++)
        #pragma unroll
        for (int j = 0; j < NR; j++)
            acc[i][j] = (f32x4){0.f, 0.f, 0.f, 0.f};

    const int rsub = ln >> 3;               // 0..7
    const int cg   = (ln & 7) ^ rsub;       // swizzled global chunk
    const ushort* gA = A  + (size_t)(row0 + wv * (MT / 4) + rsub) * K + kbase + cg * 8;
    const ushort* gB = Bt + (size_t)(col0 + wv * (NT / 4) + rsub) * K + kbase + cg * 8;
    const int fx = l15 & 7;
    const int nt = klen / 64;

    auto STAGE = [&](int buf, int kk) {
        #pragma unroll
        for (int i = 0; i < MT / 32; i++) {
            __builtin_amdgcn_global_load_lds(
                (const __attribute__((address_space(1))) void*)(gA + (size_t)i * 8 * K + kk),
                (__attribute__((address_space(3))) void*)(&As[buf * MT * 64 + (wv * (MT / 4) + i * 8) * 64]),
                16, 0, 0);
        }
        #pragma unroll
        for (int i = 0; i < NT / 32; i++) {
            __builtin_amdgcn_global_load_lds(
                (const __attribute__((address_space(1))) void*)(gB + (size_t)i * 8 * K + kk),
                (__attribute__((address_space(3))) void*)(&Bs[buf * NT * 64 + (wv * (NT / 4) + i * 8) * 64]),
                16, 0, 0);
        }
    };

    auto COMPUTE = [&](int buf) {
        #pragma unroll
        for (int s = 0; s < 2; s++) {
            const int ca = ((s * 4 + lq) ^ fx) * 8;
            bf16x8 af[MR], bfr[NR];
            #pragma unroll
            for (int mi = 0; mi < MR; mi++)
                af[mi] = *(const bf16x8*)&As[buf * MT * 64 + (wr + mi * 16 + l15) * 64 + ca];
            #pragma unroll
            for (int ni = 0; ni < NR; ni++)
                bfr[ni] = *(const bf16x8*)&Bs[buf * NT * 64 + (wc + ni * 16 + l15) * 64 + ca];
            #pragma unroll
            for (int mi = 0; mi < MR; mi++)
                #pragma unroll
                for (int ni = 0; ni < NR; ni++)
                    acc[mi][ni] = __builtin_amdgcn_mfma_f32_16x16x32_bf16(
                        af[mi], bfr[ni], acc[mi][ni], 0, 0, 0);
        }
    };

    int cur = 0;
    STAGE(0, 0);
    __syncthreads();
    for (int t = 0; t < nt; ++t) {
        const bool more = (t + 1 < nt);
        if (more) STAGE(cur ^ 1, (t + 1) * 64);
        COMPUTE(cur);
        if (more) __syncthreads();
        cur ^= 1;
    }
    __syncthreads();   // all LDS reads done before caller reuses LDS

    // Epilogue. D layout: col = lane&15, row = (lane>>4)*4 + reg.
    #pragma unroll
    for (int mi = 0; mi < MR; mi++) {
        #pragma unroll
        for (int ni = 0; ni < NR; ni++) {
            #pragma unroll
            for (int r = 0; r < 4; r++) {
                int row = row0 + wr + mi * 16 + lq * 4 + r;
                int col = col0 + wc + ni * 16 + l15;
                float v = acc[mi][ni][r];
                if (mode == 0) {
                    Cf[(size_t)row * ldc + col] = v;
                } else {
                    if (col < DD) Cb[(size_t)row * DD + col] = f2bf(fmaxf(v, 0.0f));
                    else          Cv[(size_t)row * DD + (col - DD)] = f2bf(v);
                }
            }
        }
    }
}

// ---------------- window phase: block = (b, t-tile of 32, head) ----------------
__device__ __forceinline__ void attn_phase(
    char* smem, const ushort* __restrict__ v, const float* __restrict__ Lp,
    const float* __restrict__ scale_w, ushort* __restrict__ x, int blk)
{
    ushort (*vs)[256] = (ushort (*)[256])smem;                 // 72x256 bf16 = 36,864 B
    float  (*cw)[42]  = (float  (*)[42])(smem + HB2 * 256 * 2); // 32x42 f32 = 5,376 B

    const int h  = blk & 3;
    const int tt = (blk >> 2) & 31;
    const int b  = blk >> 7;
    const int t0 = tt * TB2;
    const int tid = threadIdx.x;
    const size_t PS = (size_t)BT * NL;

    const ushort* vb = v + (size_t)b * TT * DD + h * 256;
    #pragma unroll
    for (int i = 0; i < 9; i++) {          // 72 rows x 32 uint4 = 2304 slots
        int c = i * 256 + tid;
        int r = c >> 5;
        int cir = c & 31;
        int t = t0 - HALO + r;
        uint4 val = make_uint4(0, 0, 0, 0);
        if (t >= 0 && t < TT)
            val = *(const uint4*)(vb + (size_t)t * DD + cir * 8);
        *(uint4*)(&vs[r][cir * 8]) = val;
    }

    if (tid < TB2) {
        const int bt = b * TT + t0 + tid;
        const float* Lb = Lp + (size_t)bt * NL;

        float s0 = scale_w[0], s1 = scale_w[1];
        float mm = fmaxf(s0, s1);
        float e0 = __expf(s0 - mm), e1 = __expf(s1 - mm);
        float inv01 = 1.0f / (e0 + e1);
        float sw0 = e0 * inv01, sw1 = e1 * inv01;

        float w0[C0], w1[C1];
        {
            const int off = h * C0;
            float m = -1e30f;
            #pragma unroll
            for (int j = 0; j < C0; j++) {
                float sacc = 0.0f;
                #pragma unroll
                for (int z = 0; z < KSPLIT; z++) sacc += Lb[(size_t)z * PS + off + j];
                w0[j] = sacc;
                m = fmaxf(m, w0[j]);
            }
            float s = 0.0f;
            #pragma unroll
            for (int j = 0; j < C0; j++) { w0[j] = __expf(w0[j] - m); s += w0[j]; }
            float inv = sw0 / s;
            #pragma unroll
            for (int j = 0; j < C0; j++) w0[j] *= inv;
        }
        {
            const int off = N0 + h * C1;
            float m = -1e30f;
            #pragma unroll
            for (int j = 0; j < C1; j++) {
                float sacc = 0.0f;
                #pragma unroll
                for (int z = 0; z < KSPLIT; z++) sacc += Lb[(size_t)z * PS + off + j];
                w1[j] = sacc;
                m = fmaxf(m, w1[j]);
            }
            float s = 0.0f;
            #pragma unroll
            for (int j = 0; j < C1; j++) { w1[j] = __expf(w1[j] - m); s += w1[j]; }
            float inv = sw1 / s;
            #pragma unroll
            for (int j = 0; j < C1; j++) w1[j] *= inv;
        }
        #pragma unroll
        for (int o = 0; o < C1; o++) {
            float w = w1[o];
            if (o >= 10 && o <= 30) w += w0[o - 10];
            cw[tid][o] = w;
        }
    }
    __syncthreads();

    const int tq = tid >> 6;
    const int dg = tid & 63;
    const int d  = dg * 4;

    for (int tloc = 0; tloc < 8; tloc++) {
        const int tp = tq * 8 + tloc;
        f32x4 acc = {0.f, 0.f, 0.f, 0.f};
        #pragma unroll
        for (int o = 0; o < C1; o++) {
            float w = cw[tp][o];
            ushort4 vv = *(const ushort4*)(&vs[tp + o][d]);
            acc[0] = fmaf(w, bf2f(vv.x), acc[0]);
            acc[1] = fmaf(w, bf2f(vv.y), acc[1]);
            acc[2] = fmaf(w, bf2f(vv.z), acc[2]);
            acc[3] = fmaf(w, bf2f(vv.w), acc[3]);
        }
        const int bt = b * TT + t0 + tp;
        ushort4 o4;
        o4.x = f2bf(acc[0]); o4.y = f2bf(acc[1]);
        o4.z = f2bf(acc[2]); o4.w = f2bf(acc[3]);
        *(ushort4*)(x + (size_t)bt * DD + h * 256 + d) = o4;
    }
    __syncthreads();   // LDS reads done before next phase reuses LDS
}

// ---------------- persistent fused kernel: qv -> logits -> window -> out ----------------
// 512 blocks (2/CU, 64 KB LDS each) stay resident; phases separated by software
// grid barriers (relaxed-poll, single-fence). GEMM phases use XCD-chunked tile
// remap so each XCD's L2 serves a contiguous slab of A-panels.
__global__ __launch_bounds__(256, 2) void mega(
    const ushort* __restrict__ query_bf, const ushort* __restrict__ WqvT,
    const ushort* __restrict__ W2T, const ushort* __restrict__ WoutT,
    ushort* __restrict__ reluq, ushort* __restrict__ vbuf,
    float* __restrict__ logitsP, ushort* __restrict__ xbuf,
    const float* __restrict__ scale_w, float* __restrict__ out,
    uint* __restrict__ bar)
{
    __shared__ __attribute__((aligned(16))) char smem[65536];
    ushort* lds = (ushort*)smem;
    const int blk = blockIdx.x;

    // Phase A: qv GEMM [4096,1024]x[1024,2048], 512 tiles of 128x128 (1 each)
    {
        const int tile = xcd_chunk(blk, NBLK);
        const int bx = tile & 15;         // 16 N-tiles over 2048
        const int by = tile >> 4;         // 32 M-tiles over 4096
        gemm_phase<128, 128>(lds, query_bf, WqvT, DD, DD, 0,
                             by * 128, bx * 128,
                             nullptr, reluq, vbuf, 2, 0);
    }
    grid_barrier(bar);

    // Phase B: logits GEMM relu(q) x W2T, 64x64 tiles, split-K=2 -> 512 tiles
    {
        const int tile = xcd_chunk(blk, NBLK);
        const int bz = tile & 1;
        const int bx = (tile >> 1) & 3;   // 4 N-tiles over 256
        const int by = tile >> 3;         // 64 M-tiles over 4096
        gemm_phase<64, 64>(lds, reluq, W2T, DD, DD / KSPLIT, bz * (DD / KSPLIT),
                           by * 64, bx * 64,
                           logitsP + (size_t)bz * BT * NL, nullptr, nullptr, 0, NL);
    }
    grid_barrier(bar);

    // Phase C: softmax + sliding window -> xbuf
    attn_phase(smem, vbuf, logitsP, scale_w, xbuf, blk);
    grid_barrier(bar);

    // Phase D: out GEMM x @ WoutT, 128x64 tiles -> 512 tiles (1 each)
    {
        const int tile = xcd_chunk(blk, NBLK);
        const int bx = tile & 15;         // 16 N-tiles over 1024
        const int by = tile >> 4;         // 32 M-tiles over 4096
        gemm_phase<128, 64>(lds, xbuf, WoutT, DD, DD, 0,
                            by * 128, bx * 64,
                            out, nullptr, nullptr, 0, DD);
    }
}

// ---------------------------------- launch ----------------------------------
extern "C" void kernel_launch(void* const* d_in, const int* in_sizes, int n_in,
                              void* d_out, int out_size, void* d_ws, size_t ws_size,
                              hipStream_t stream)
{
    const float* query   = (const float*)d_in[0];
    const float* W_qv    = (const float*)d_in[3];
    const float* W2_0    = (const float*)d_in[4];
    const float* W2_1    = (const float*)d_in[5];
    const float* scale_w = (const float*)d_in[6];
    const float* W_out   = (const float*)d_in[7];
    float* out = (float*)d_out;

    // Workspace layout
    char* ws = (char*)d_ws;
    ushort* W2T      = (ushort*)ws;                 ws += (size_t)NL * DD * 2;          // 0.5 MB
    ushort* WoutT    = (ushort*)ws;                 ws += (size_t)DD * DD * 2;          // 2 MB
    ushort* query_bf = (ushort*)ws;                 ws += (size_t)BT * DD * 2;          // 8 MB
    ushort* WqvT     = (ushort*)ws;                 ws += (size_t)2 * DD * DD * 2;      // 4 MB
    ushort* reluq    = (ushort*)ws;                 ws += (size_t)BT * DD * 2;          // 8 MB
    ushort* vbuf     = (ushort*)ws;                 ws += (size_t)BT * DD * 2;          // 8 MB
    ushort* xbuf     = (ushort*)ws;                 ws += (size_t)BT * DD * 2;          // 8 MB
    float*  logitsP  = (float*)ws;                  ws += (size_t)KSPLIT * BT * NL * 4; // 8 MB
    uint*   bar      = (uint*)ws;                   ws += 4096;

    // 0) conversions + barrier re-arm
    convert_all<<<R4, 256, 0, stream>>>(query, query_bf, W_qv, WqvT,
                                        W_out, WoutT, W2_0, W2_1, W2T, bar);

    // 1) fused persistent chain: qv -> logits -> window -> out
    mega<<<NBLK, 256, 0, stream>>>(query_bf, WqvT, W2T, WoutT,
                                   reluq, vbuf, logitsP, xbuf,
                                   scale_w, out, bar);
}

// Round 6
// 177.271 us; speedup vs baseline: 2.0561x; 1.8249x over previous
//
#include <hip/hip_runtime.h>
#include <hip/hip_bf16.h>
#include <math.h>

// Problem dims (fixed by reference)
#define BB 4
#define TT 1024
#define DD 1024
#define HPS 4          // heads per scale
#define C0 21
#define C1 41
#define N0 (HPS * C0)  // 84
#define N1 (HPS * C1)  // 164
#define NL 256         // padded combined logits width (84 + 164 = 248 -> 256)
#define BT (BB * TT)   // 4096
#define KSPLIT 4       // split-K for logits GEMM
#define TB2 32         // t-tile for window kernel (512 blocks -> 2/CU)
#define HALO 20
#define HB2 (TB2 + 2 * HALO)  // 72 rows staged

typedef unsigned int uint;
typedef __bf16 bf16x8 __attribute__((ext_vector_type(8)));
typedef float f32x4 __attribute__((ext_vector_type(4)));

__device__ __forceinline__ ushort f2bf(float f) {
    union { float f; uint u; } v; v.f = f;
    uint u = v.u;
    uint r = (u + 0x7FFFu + ((u >> 16) & 1u)) >> 16;
    return (ushort)r;
}
__device__ __forceinline__ float bf2f(ushort s) {
    union { uint u; float f; } v; v.u = ((uint)s) << 16;
    return v.f;
}

// ---------------- fused conversion kernel ----------------
#define RQ  4096
#define R1  (RQ + 2048)
#define R2  (R1 + 1024)
#define R3  (R2 + 96)
#define R4  (R3 + 192)

__device__ __forceinline__ void transpose_tile(
    const float* __restrict__ in, ushort* __restrict__ out,
    int K, int Nin, int n_base, int Npad, int nx, int ky, int tid)
{
    __shared__ float tile[32][33];
    const int tx = tid & 31;
    const int ty = tid >> 5;   // 0..7
    const int n0 = nx * 32;
    const int k0 = ky * 32;
    #pragma unroll
    for (int i = 0; i < 4; i++) {
        int k = k0 + ty + i * 8;
        int n = n0 + tx;
        float v = (k < K && n < Nin) ? in[(size_t)k * Nin + n] : 0.0f;
        tile[ty + i * 8][tx] = v;
    }
    __syncthreads();
    #pragma unroll
    for (int i = 0; i < 4; i++) {
        int n = n0 + ty + i * 8;
        int k = k0 + tx;
        if (n < Npad && k < K)
            out[(size_t)(n_base + n) * K + k] = f2bf(tile[tx][ty + i * 8]);
    }
}

__global__ __launch_bounds__(256) void convert_all(
    const float* __restrict__ query, ushort* __restrict__ query_bf,
    const float* __restrict__ W_qv,  ushort* __restrict__ WqvT,
    const float* __restrict__ W_out, ushort* __restrict__ WoutT,
    const float* __restrict__ W2_0, const float* __restrict__ W2_1,
    ushort* __restrict__ W2T)
{
    const int blk = blockIdx.x;
    const int tid = threadIdx.x;
    if (blk < RQ) {
        int i = blk * 1024 + tid * 4;
        float4 v = *(const float4*)(query + i);
        ushort4 o;
        o.x = f2bf(v.x); o.y = f2bf(v.y); o.z = f2bf(v.z); o.w = f2bf(v.w);
        *(ushort4*)(query_bf + i) = o;
    } else if (blk < R1) {
        int idx = blk - RQ;                // 64 x 32
        transpose_tile(W_qv, WqvT, DD, 2 * DD, 0, 2 * DD, idx & 63, idx >> 6, tid);
    } else if (blk < R2) {
        int idx = blk - R1;                // 32 x 32
        transpose_tile(W_out, WoutT, DD, DD, 0, DD, idx & 31, idx >> 5, tid);
    } else if (blk < R3) {
        int idx = blk - R2;                // 3 x 32
        transpose_tile(W2_0, W2T, DD, N0, 0, N0, idx % 3, idx / 3, tid);
    } else {
        int idx = blk - R3;                // 6 x 32
        transpose_tile(W2_1, W2T, DD, N1, N0, NL - N0, idx % 6, idx / 6, tid);
    }
}

// XCD-chunked bijective tile remap (T1). The dispatcher round-robins blocks
// across the 8 XCDs; remapping tile = (blk%8)*(n/8) + blk/8 gives each XCD a
// CONTIGUOUS logical-tile slab (contiguous by-rows since tiles are by-major),
// so a shared A-panel fills ONE XCD's L2 instead of being re-fetched into 8.
// Requires n % 8 == 0 (all our per-z tile counts are 128 or 512).
__device__ __forceinline__ int xcd_chunk(int blk, int nblk) {
    return (blk & 7) * (nblk >> 3) + (blk >> 3);
}

// ------ bf16 MFMA GEMM, 8-wave (512-thr) block, MTxNT tile, BK=64 dbuf ------
// A: [M][K] bf16 row-major. Bt: [N][K] bf16 row-major. K,klen multiples of 64.
// MT = 128; NT in {64,128}. 8 waves in 2(M) x 4(N) grid: wave owns 64 x NT/4.
// KEY CHANGE vs rounds 0-3 (all 4-wave): 16 waves/CU (2 blocks x 8) -> 4
// waves/SIMD, so while one block sits in its staging wait the SIMD still has
// 2 MFMA-issuing waves from the other block (was 1). Latency hiding via TLP.
// LDS per buffer: [row][chunk 0..7][8 ushort]; slot (r,c) holds global chunk
// c^(r&7). Staging instr covers 64 rows x 128B: lane l -> row base+(l>>3),
// slot l&7 -> global chunk (l&7)^(l>>3) (all row bases are multiples of 8).
// Fragment ds_read xor fx=l15&7 -> 2-way bank aliasing (free).
// mode 0: Cf[row*ldc+col] = acc
// mode 2: col<DD -> Cb[row*DD+col]=bf16(relu(acc)); else Cv[row*DD+col-DD]=bf16(acc)
// mode 3: Cf[(bz*BT + row)*ldc + col] = acc   (split-K partial)
template<int NT>
__global__ __launch_bounds__(512, 4) void gemm_mfma(
    const ushort* __restrict__ A, const ushort* __restrict__ Bt,
    int K, int klen,
    float* __restrict__ Cf, ushort* __restrict__ Cb, ushort* __restrict__ Cv,
    int mode, int ldc)
{
    constexpr int MT = 128;
    constexpr int MR = 4;          // 64 / 16
    constexpr int NR = NT / 64;    // wave N-frags: NT=128 -> 2, NT=64 -> 1
    __shared__ ushort As[2][MT * 64];   // 2 x 16 KB
    __shared__ ushort Bs[2][NT * 64];   // 2 x (16 or 8) KB; total 64/48 KB

    const int tid = threadIdx.x;
    const int wv  = tid >> 6;          // 0..7
    const int ln  = tid & 63;

    // XCD-chunked tile remap over the (gridDim.x * gridDim.y) tile space
    const int ntile = gridDim.x * gridDim.y;
    const int tile  = xcd_chunk(blockIdx.y * gridDim.x + blockIdx.x, ntile);
    const int bx = tile % gridDim.x;
    const int by = tile / gridDim.x;
    const int row0 = by * MT;
    const int col0 = bx * NT;
    const int kbase = blockIdx.z * klen;

    const int wr = (wv >> 2) * 64;        // wave M offset: 0/64
    const int wc = (wv & 3) * (NT / 4);   // wave N offset
    const int l15 = ln & 15;
    const int lq  = ln >> 4;              // 0..3

    f32x4 acc[MR][NR];
    #pragma unroll
    for (int i = 0; i < MR; i++)
        #pragma unroll
        for (int j = 0; j < NR; j++)
            acc[i][j] = (f32x4){0.f, 0.f, 0.f, 0.f};

    // staging: instr covers rows base + wv*8 + (l>>3); chunk (l&7)^(l>>3)
    const int rsub = ln >> 3;             // 0..7
    const int cg   = (ln & 7) ^ rsub;
    const ushort* gA = A  + (size_t)(row0 + wv * 8 + rsub) * K + kbase + cg * 8;
    const ushort* gB = Bt + (size_t)(col0 + wv * 8 + rsub) * K + kbase + cg * 8;
    const int fx = l15 & 7;
    const int nt = klen / 64;

    auto STAGE = [&](int buf, int kk) {
        #pragma unroll
        for (int i = 0; i < 2; i++) {     // A: 2 instrs cover 128 rows
            __builtin_amdgcn_global_load_lds(
                (const __attribute__((address_space(1))) void*)(gA + (size_t)i * 64 * K + kk),
                (__attribute__((address_space(3))) void*)(&As[buf][(i * 64 + wv * 8) * 64]),
                16, 0, 0);
        }
        #pragma unroll
        for (int i = 0; i < NT / 64; i++) {  // B: NT/64 instrs
            __builtin_amdgcn_global_load_lds(
                (const __attribute__((address_space(1))) void*)(gB + (size_t)i * 64 * K + kk),
                (__attribute__((address_space(3))) void*)(&Bs[buf][(i * 64 + wv * 8) * 64]),
                16, 0, 0);
        }
    };

    auto COMPUTE = [&](int buf) {
        #pragma unroll
        for (int s = 0; s < 2; s++) {
            const int ca = ((s * 4 + lq) ^ fx) * 8;
            bf16x8 af[MR], bfr[NR];
            #pragma unroll
            for (int mi = 0; mi < MR; mi++)
                af[mi] = *(const bf16x8*)&As[buf][(wr + mi * 16 + l15) * 64 + ca];
            #pragma unroll
            for (int ni = 0; ni < NR; ni++)
                bfr[ni] = *(const bf16x8*)&Bs[buf][(wc + ni * 16 + l15) * 64 + ca];
            #pragma unroll
            for (int mi = 0; mi < MR; mi++)
                #pragma unroll
                for (int ni = 0; ni < NR; ni++)
                    acc[mi][ni] = __builtin_amdgcn_mfma_f32_16x16x32_bf16(
                        af[mi], bfr[ni], acc[mi][ni], 0, 0, 0);
        }
    };

    int cur = 0;
    STAGE(0, 0);
    __syncthreads();                        // buf0 visible
    for (int t = 0; t < nt; ++t) {
        const bool more = (t + 1 < nt);     // block-uniform
        if (more) STAGE(cur ^ 1, (t + 1) * 64);
        COMPUTE(cur);
        if (more) __syncthreads();          // drain + handoff
        cur ^= 1;
    }

    // Epilogue. D layout: col = lane&15, row = (lane>>4)*4 + reg.
    #pragma unroll
    for (int mi = 0; mi < MR; mi++) {
        #pragma unroll
        for (int ni = 0; ni < NR; ni++) {
            #pragma unroll
            for (int r = 0; r < 4; r++) {
                int row = row0 + wr + mi * 16 + lq * 4 + r;
                int col = col0 + wc + ni * 16 + l15;
                float v = acc[mi][ni][r];
                if (mode == 0) {
                    Cf[(size_t)row * ldc + col] = v;
                } else if (mode == 2) {
                    if (col < DD) Cb[(size_t)row * DD + col] = f2bf(fmaxf(v, 0.0f));
                    else          Cv[(size_t)row * DD + (col - DD)] = f2bf(v);
                } else {
                    Cf[((size_t)blockIdx.z * BT + row) * ldc + col] = v;
                }
            }
        }
    }
}

// ------------- window kernel: 512 blocks = (b, t-tile of 32, head), 2/CU -------------
__global__ __launch_bounds__(256) void attn_window_kernel(
    const ushort* __restrict__ v,
    const float* __restrict__ Lp,
    const float* __restrict__ scale_w,
    ushort* __restrict__ x)
{
    __shared__ ushort vs[HB2][256];   // 36,864 B
    __shared__ float  cw[TB2][42];    //  5,376 B

    const int blk = blockIdx.x;       // 512 blocks
    const int h  = blk & 3;
    const int tt = (blk >> 2) & 31;
    const int b  = blk >> 7;
    const int t0 = tt * TB2;
    const int tid = threadIdx.x;
    const size_t PS = (size_t)BT * NL;

    const ushort* vb = v + (size_t)b * TT * DD + h * 256;
    #pragma unroll
    for (int i = 0; i < 9; i++) {     // 72 rows x 32 uint4 = 2304 slots
        int c = i * 256 + tid;
        int r = c >> 5;
        int cir = c & 31;
        int t = t0 - HALO + r;
        uint4 val = make_uint4(0, 0, 0, 0);
        if (t >= 0 && t < TT)
            val = *(const uint4*)(vb + (size_t)t * DD + cir * 8);
        *(uint4*)(&vs[r][cir * 8]) = val;
    }

    if (tid < TB2) {
        const int bt = b * TT + t0 + tid;
        const float* Lb = Lp + (size_t)bt * NL;

        float s0 = scale_w[0], s1 = scale_w[1];
        float mm = fmaxf(s0, s1);
        float e0 = __expf(s0 - mm), e1 = __expf(s1 - mm);
        float inv01 = 1.0f / (e0 + e1);
        float sw0 = e0 * inv01, sw1 = e1 * inv01;

        float w0[C0], w1[C1];
        {
            const int off = h * C0;
            float m = -1e30f;
            #pragma unroll
            for (int j = 0; j < C0; j++) {
                float sacc = 0.0f;
                #pragma unroll
                for (int z = 0; z < KSPLIT; z++) sacc += Lb[(size_t)z * PS + off + j];
                w0[j] = sacc;
                m = fmaxf(m, w0[j]);
            }
            float s = 0.0f;
            #pragma unroll
            for (int j = 0; j < C0; j++) { w0[j] = __expf(w0[j] - m); s += w0[j]; }
            float inv = sw0 / s;
            #pragma unroll
            for (int j = 0; j < C0; j++) w0[j] *= inv;
        }
        {
            const int off = N0 + h * C1;
            float m = -1e30f;
            #pragma unroll
            for (int j = 0; j < C1; j++) {
                float sacc = 0.0f;
                #pragma unroll
                for (int z = 0; z < KSPLIT; z++) sacc += Lb[(size_t)z * PS + off + j];
                w1[j] = sacc;
                m = fmaxf(m, w1[j]);
            }
            float s = 0.0f;
            #pragma unroll
            for (int j = 0; j < C1; j++) { w1[j] = __expf(w1[j] - m); s += w1[j]; }
            float inv = sw1 / s;
            #pragma unroll
            for (int j = 0; j < C1; j++) w1[j] *= inv;
        }
        #pragma unroll
        for (int o = 0; o < C1; o++) {
            float w = w1[o];
            if (o >= 10 && o <= 30) w += w0[o - 10];
            cw[tid][o] = w;
        }
    }
    __syncthreads();

    const int tq = tid >> 6;
    const int dg = tid & 63;
    const int d  = dg * 4;

    for (int tloc = 0; tloc < 8; tloc++) {
        const int tp = tq * 8 + tloc;
        f32x4 acc = {0.f, 0.f, 0.f, 0.f};
        #pragma unroll
        for (int o = 0; o < C1; o++) {
            float w = cw[tp][o];
            ushort4 vv = *(const ushort4*)(&vs[tp + o][d]);
            acc[0] = fmaf(w, bf2f(vv.x), acc[0]);
            acc[1] = fmaf(w, bf2f(vv.y), acc[1]);
            acc[2] = fmaf(w, bf2f(vv.z), acc[2]);
            acc[3] = fmaf(w, bf2f(vv.w), acc[3]);
        }
        const int bt = b * TT + t0 + tp;
        ushort4 o4;
        o4.x = f2bf(acc[0]); o4.y = f2bf(acc[1]);
        o4.z = f2bf(acc[2]); o4.w = f2bf(acc[3]);
        *(ushort4*)(x + (size_t)bt * DD + h * 256 + d) = o4;
    }
}

// ---------------------------------- launch ----------------------------------
extern "C" void kernel_launch(void* const* d_in, const int* in_sizes, int n_in,
                              void* d_out, int out_size, void* d_ws, size_t ws_size,
                              hipStream_t stream)
{
    const float* query   = (const float*)d_in[0];
    const float* W_qv    = (const float*)d_in[3];
    const float* W2_0    = (const float*)d_in[4];
    const float* W2_1    = (const float*)d_in[5];
    const float* scale_w = (const float*)d_in[6];
    const float* W_out   = (const float*)d_in[7];
    float* out = (float*)d_out;

    // Workspace layout (logitsP = KSPLIT x 4 MB = 16 MB)
    char* ws = (char*)d_ws;
    ushort* W2T      = (ushort*)ws;                 ws += (size_t)NL * DD * 2;          // 0.5 MB
    ushort* WoutT    = (ushort*)ws;                 ws += (size_t)DD * DD * 2;          // 2 MB
    ushort* query_bf = (ushort*)ws;                 ws += (size_t)BT * DD * 2;          // 8 MB
    ushort* WqvT     = (ushort*)ws;                 ws += (size_t)2 * DD * DD * 2;      // 4 MB
    ushort* reluq    = (ushort*)ws;                 ws += (size_t)BT * DD * 2;          // 8 MB
    ushort* vbuf     = (ushort*)ws;                 ws += (size_t)BT * DD * 2;          // 8 MB
    ushort* xbuf     = (ushort*)ws;                 ws += (size_t)BT * DD * 2;          // 8 MB
    float*  logitsP  = (float*)ws;                  ws += (size_t)KSPLIT * BT * NL * 4; // 16 MB

    // 0) all conversions in one launch
    convert_all<<<R4, 256, 0, stream>>>(query, query_bf, W_qv, WqvT,
                                        W_out, WoutT, W2_0, W2_1, W2T);

    // 1) qv GEMM: [4096,1024]x[1024,2048] -> reluq + vbuf (512 blocks x 512 thr)
    {   dim3 grid(2 * DD / 128, BT / 128, 1);
        gemm_mfma<128><<<grid, 512, 0, stream>>>(query_bf, WqvT, DD, DD,
                                                 nullptr, reluq, vbuf, 2, 0); }
    // 2) logits GEMM split-K=4: relu(q) x W2T -> logitsP (512 blocks)
    {   dim3 grid(NL / 64, BT / 128, KSPLIT);
        gemm_mfma<64><<<grid, 512, 0, stream>>>(reluq, W2T, DD, DD / KSPLIT,
                                                logitsP, nullptr, nullptr, 3, NL); }
    // 3) softmax (+partial sum) + sliding window -> xbuf (512 blocks)
    attn_window_kernel<<<512, 256, 0, stream>>>(vbuf, logitsP, scale_w, xbuf);

    // 4) out GEMM: x x WoutT -> out f32 (512 blocks)
    {   dim3 grid(DD / 64, BT / 128, 1);
        gemm_mfma<64><<<grid, 512, 0, stream>>>(xbuf, WoutT, DD, DD,
                                                out, nullptr, nullptr, 0, DD); }
}

// Round 7
// 168.107 us; speedup vs baseline: 2.1682x; 1.0545x over previous
//
#include <hip/hip_runtime.h>
#include <hip/hip_bf16.h>
#include <math.h>

// Problem dims (fixed by reference)
#define BB 4
#define TT 1024
#define DD 1024
#define HPS 4          // heads per scale
#define C0 21
#define C1 41
#define N0 (HPS * C0)  // 84
#define N1 (HPS * C1)  // 164
#define BT (BB * TT)   // 4096
#define TB2 32         // t-tile for window kernel (512 blocks -> 2/CU)
#define HALO 20
#define HB2 (TB2 + 2 * HALO)  // 72 rows staged

typedef unsigned int uint;
typedef __bf16 bf16x8 __attribute__((ext_vector_type(8)));
typedef float f32x4 __attribute__((ext_vector_type(4)));

__device__ __forceinline__ ushort f2bf(float f) {
    union { float f; uint u; } v; v.f = f;
    uint u = v.u;
    uint r = (u + 0x7FFFu + ((u >> 16) & 1u)) >> 16;
    return (ushort)r;
}
__device__ __forceinline__ float bf2f(ushort s) {
    union { uint u; float f; } v; v.u = ((uint)s) << 16;
    return v.f;
}

// ---------------- fused conversion kernel ----------------
#define RQ  4096
#define R1  (RQ + 2048)
#define R2  (R1 + 1024)
#define R3  (R2 + 96)
#define R4  (R3 + 192)

// Transpose [K][Nin] f32 -> bf16 [row][K] where row = (n/hs)*rstride + roff + n%hs.
// hs >= Nin gives the linear mapping row = n (used for W_qv, W_out).
// For W2 the per-head remap packs head h's columns into rows h*64+roff.. so the
// fused attn kernel can stage its head slice as a dense aligned [64][K] matrix.
__device__ __forceinline__ void transpose_tile(
    const float* __restrict__ in, ushort* __restrict__ out,
    int K, int Nin, int nx, int ky, int tid, int hs, int roff)
{
    __shared__ float tile[32][33];
    const int tx = tid & 31;
    const int ty = tid >> 5;   // 0..7
    const int n0 = nx * 32;
    const int k0 = ky * 32;
    #pragma unroll
    for (int i = 0; i < 4; i++) {
        int k = k0 + ty + i * 8;
        int n = n0 + tx;
        float v = (k < K && n < Nin) ? in[(size_t)k * Nin + n] : 0.0f;
        tile[ty + i * 8][tx] = v;
    }
    __syncthreads();
    #pragma unroll
    for (int i = 0; i < 4; i++) {
        int n = n0 + ty + i * 8;
        int k = k0 + tx;
        if (n < Nin && k < K) {
            int row = (n / hs) * 64 + roff + (n % hs);
            out[(size_t)row * K + k] = f2bf(tile[tx][ty + i * 8]);
        }
    }
}

__global__ __launch_bounds__(256) void convert_all(
    const float* __restrict__ query, ushort* __restrict__ query_bf,
    const float* __restrict__ W_qv,  ushort* __restrict__ WqvT,
    const float* __restrict__ W_out, ushort* __restrict__ WoutT,
    const float* __restrict__ W2_0, const float* __restrict__ W2_1,
    ushort* __restrict__ W2Tph)
{
    const int blk = blockIdx.x;
    const int tid = threadIdx.x;
    if (blk < RQ) {
        int i = blk * 1024 + tid * 4;
        float4 v = *(const float4*)(query + i);
        ushort4 o;
        o.x = f2bf(v.x); o.y = f2bf(v.y); o.z = f2bf(v.z); o.w = f2bf(v.w);
        *(ushort4*)(query_bf + i) = o;
    } else if (blk < R1) {
        int idx = blk - RQ;                // 64 x 32 tiles, linear rows
        transpose_tile(W_qv, WqvT, DD, 2 * DD, idx & 63, idx >> 6, tid, 2 * DD, 0);
    } else if (blk < R2) {
        int idx = blk - R1;                // 32 x 32 tiles, linear rows
        transpose_tile(W_out, WoutT, DD, DD, idx & 31, idx >> 5, tid, DD, 0);
    } else if (blk < R3) {
        int idx = blk - R2;                // 3 x 32: scale0 -> rows h*64 + 0..20
        transpose_tile(W2_0, W2Tph, DD, N0, idx % 3, idx / 3, tid, C0, 0);
    } else {
        int idx = blk - R3;                // 6 x 32: scale1 -> rows h*64 + 21..61
        transpose_tile(W2_1, W2Tph, DD, N1, idx % 6, idx / 6, tid, C1, C0);
    }
}

// XCD-chunked bijective tile remap (T1). The dispatcher round-robins blocks
// across the 8 XCDs; remapping tile = (blk%8)*(n/8) + blk/8 gives each XCD a
// CONTIGUOUS logical-tile slab, so a shared A-panel fills ONE XCD's L2.
// Requires n % 8 == 0.
__device__ __forceinline__ int xcd_chunk(int blk, int nblk) {
    return (blk & 7) * (nblk >> 3) + (blk >> 3);
}

// ------ bf16 MFMA GEMM, 8-wave (512-thr) block, 128xNT tile, BK=64 dbuf ------
// A: [M][K] bf16 row-major. Bt: [N][K] bf16 row-major. K,klen multiples of 64.
// 8 waves in 2(M) x 4(N) grid: wave owns 64 x NT/4. 16 waves/CU (2 blocks x 8)
// -> 4 waves/SIMD for TLP latency hiding (the R6 win).
// LDS per buffer: [row][chunk 0..7][8 ushort]; slot (r,c) holds global chunk
// c^(r&7). Staging lane l -> row base+(l>>3), slot l&7 -> global chunk
// (l&7)^(l>>3) (row bases are multiples of 8). Fragment read xor fx=l15&7.
// mode 0: Cf[row*ldc+col] = acc
// mode 2: col<DD -> Cb[row*DD+col]=bf16(relu(acc)); else Cv[row*DD+col-DD]=bf16(acc)
template<int NT>
__global__ __launch_bounds__(512, 4) void gemm_mfma(
    const ushort* __restrict__ A, const ushort* __restrict__ Bt,
    int K, int klen,
    float* __restrict__ Cf, ushort* __restrict__ Cb, ushort* __restrict__ Cv,
    int mode, int ldc)
{
    constexpr int MT = 128;
    constexpr int MR = 4;          // 64 / 16
    constexpr int NR = NT / 64;    // wave N-frags: NT=128 -> 2, NT=64 -> 1
    __shared__ ushort As[2][MT * 64];   // 2 x 16 KB
    __shared__ ushort Bs[2][NT * 64];   // 2 x (16 or 8) KB

    const int tid = threadIdx.x;
    const int wv  = tid >> 6;          // 0..7
    const int ln  = tid & 63;

    const int ntile = gridDim.x * gridDim.y;
    const int tile  = xcd_chunk(blockIdx.y * gridDim.x + blockIdx.x, ntile);
    const int bx = tile % gridDim.x;
    const int by = tile / gridDim.x;
    const int row0 = by * MT;
    const int col0 = bx * NT;
    const int kbase = blockIdx.z * klen;

    const int wr = (wv >> 2) * 64;        // wave M offset: 0/64
    const int wc = (wv & 3) * (NT / 4);   // wave N offset
    const int l15 = ln & 15;
    const int lq  = ln >> 4;              // 0..3

    f32x4 acc[MR][NR];
    #pragma unroll
    for (int i = 0; i < MR; i++)
        #pragma unroll
        for (int j = 0; j < NR; j++)
            acc[i][j] = (f32x4){0.f, 0.f, 0.f, 0.f};

    const int rsub = ln >> 3;             // 0..7
    const int cg   = (ln & 7) ^ rsub;
    const ushort* gA = A  + (size_t)(row0 + wv * 8 + rsub) * K + kbase + cg * 8;
    const ushort* gB = Bt + (size_t)(col0 + wv * 8 + rsub) * K + kbase + cg * 8;
    const int fx = l15 & 7;
    const int nt = klen / 64;

    auto STAGE = [&](int buf, int kk) {
        #pragma unroll
        for (int i = 0; i < 2; i++) {     // A: 2 instrs cover 128 rows
            __builtin_amdgcn_global_load_lds(
                (const __attribute__((address_space(1))) void*)(gA + (size_t)i * 64 * K + kk),
                (__attribute__((address_space(3))) void*)(&As[buf][(i * 64 + wv * 8) * 64]),
                16, 0, 0);
        }
        #pragma unroll
        for (int i = 0; i < NT / 64; i++) {  // B: NT/64 instrs
            __builtin_amdgcn_global_load_lds(
                (const __attribute__((address_space(1))) void*)(gB + (size_t)i * 64 * K + kk),
                (__attribute__((address_space(3))) void*)(&Bs[buf][(i * 64 + wv * 8) * 64]),
                16, 0, 0);
        }
    };

    auto COMPUTE = [&](int buf) {
        #pragma unroll
        for (int s = 0; s < 2; s++) {
            const int ca = ((s * 4 + lq) ^ fx) * 8;
            bf16x8 af[MR], bfr[NR];
            #pragma unroll
            for (int mi = 0; mi < MR; mi++)
                af[mi] = *(const bf16x8*)&As[buf][(wr + mi * 16 + l15) * 64 + ca];
            #pragma unroll
            for (int ni = 0; ni < NR; ni++)
                bfr[ni] = *(const bf16x8*)&Bs[buf][(wc + ni * 16 + l15) * 64 + ca];
            #pragma unroll
            for (int mi = 0; mi < MR; mi++)
                #pragma unroll
                for (int ni = 0; ni < NR; ni++)
                    acc[mi][ni] = __builtin_amdgcn_mfma_f32_16x16x32_bf16(
                        af[mi], bfr[ni], acc[mi][ni], 0, 0, 0);
        }
    };

    int cur = 0;
    STAGE(0, 0);
    __syncthreads();
    for (int t = 0; t < nt; ++t) {
        const bool more = (t + 1 < nt);
        if (more) STAGE(cur ^ 1, (t + 1) * 64);
        COMPUTE(cur);
        if (more) __syncthreads();
        cur ^= 1;
    }

    // Epilogue. D layout: col = lane&15, row = (lane>>4)*4 + reg.
    #pragma unroll
    for (int mi = 0; mi < MR; mi++) {
        #pragma unroll
        for (int ni = 0; ni < NR; ni++) {
            #pragma unroll
            for (int r = 0; r < 4; r++) {
                int row = row0 + wr + mi * 16 + lq * 4 + r;
                int col = col0 + wc + ni * 16 + l15;
                float v = acc[mi][ni][r];
                if (mode == 0) {
                    Cf[(size_t)row * ldc + col] = v;
                } else {
                    if (col < DD) Cb[(size_t)row * DD + col] = f2bf(fmaxf(v, 0.0f));
                    else          Cv[(size_t)row * DD + (col - DD)] = f2bf(v);
                }
            }
        }
    }
}

// ---- fused logits + softmax + sliding-window kernel ----
// 512 blocks = (b, t-tile of 32, head), 256 threads, ~75 KB dynamic LDS (2/CU).
// Replaces the separate logits GEMM + logitsP round-trip: each block computes
// its own 32x62 logits slice (K=1024) with MFMA from reluq and the per-head
// repacked W2Tph[h] [64][1024], writes frags to LDS, then does softmax +
// window sum exactly as before.
#define LOFF_VS 0
#define LOFF_QS (LOFF_VS + HB2 * 256 * 2)            // 36864
#define LOFF_WS (LOFF_QS + 2 * TB2 * 64 * 2)         // +8192 = 45056
#define LOFF_LS (LOFF_WS + 2 * 64 * 64 * 2)          // +16384 = 61440
#define LOFF_CW (LOFF_LS + TB2 * 65 * 4)             // +8320 = 69760
#define LDS_TOTAL (LOFF_CW + TB2 * 42 * 4)           // +5376 = 75136

__global__ __launch_bounds__(256) void attn_fused_kernel(
    const ushort* __restrict__ reluq,
    const ushort* __restrict__ W2Tph,   // [4][64][1024] bf16
    const ushort* __restrict__ v,
    const float* __restrict__ scale_w,
    ushort* __restrict__ x)
{
    extern __shared__ __attribute__((aligned(16))) char smem[];
    ushort (*vs)[256] = (ushort (*)[256])(smem + LOFF_VS);
    ushort* qs = (ushort*)(smem + LOFF_QS);          // [2][32*64]
    ushort* ws2 = (ushort*)(smem + LOFF_WS);         // [2][64*64]
    float  (*Ls)[65] = (float (*)[65])(smem + LOFF_LS);
    float  (*cw)[42] = (float (*)[42])(smem + LOFF_CW);

    const int blk = blockIdx.x;       // 512 blocks
    const int h  = blk & 3;
    const int tt = (blk >> 2) & 31;
    const int b  = blk >> 7;
    const int t0 = tt * TB2;
    const int tid = threadIdx.x;
    const int bt0 = b * TT + t0;

    // ---- v window staging (72 rows x 256 bf16) ----
    const ushort* vb = v + (size_t)b * TT * DD + h * 256;
    #pragma unroll
    for (int i = 0; i < 9; i++) {
        int c = i * 256 + tid;
        int r = c >> 5;
        int cir = c & 31;
        int t = t0 - HALO + r;
        uint4 val = make_uint4(0, 0, 0, 0);
        if (t >= 0 && t < TT)
            val = *(const uint4*)(vb + (size_t)t * DD + cir * 8);
        *(uint4*)(&vs[r][cir * 8]) = val;
    }

    // ---- QK GEMM: logits[32][64] = reluq rows x W2Tph[h]^T, K=1024 ----
    const int wv = tid >> 6;          // 0..3
    const int ln = tid & 63;
    const int wr = (wv >> 1) * 16;    // wave M offset: 0/16
    const int wc = (wv & 1) * 32;     // wave N offset: 0/32
    const int l15 = ln & 15;
    const int lq  = ln >> 4;
    const int rsub = ln >> 3;
    const int cg   = (ln & 7) ^ rsub;           // swizzled global chunk
    const int fx = l15 & 7;

    const ushort* gA = reluq + (size_t)(bt0 + wv * 8 + rsub) * DD + cg * 8;
    const ushort* gB = W2Tph + ((size_t)h * 64 + wv * 16 + rsub) * DD + cg * 8;

    f32x4 acc[2];
    acc[0] = (f32x4){0.f, 0.f, 0.f, 0.f};
    acc[1] = (f32x4){0.f, 0.f, 0.f, 0.f};

    auto STAGEQ = [&](int buf, int kk) {
        // A: 4 waves x 1 instr cover 32 rows
        __builtin_amdgcn_global_load_lds(
            (const __attribute__((address_space(1))) void*)(gA + kk),
            (__attribute__((address_space(3))) void*)(&qs[(size_t)buf * TB2 * 64 + (wv * 8) * 64]),
            16, 0, 0);
        // B: 4 waves x 2 instrs cover 64 rows
        #pragma unroll
        for (int i = 0; i < 2; i++) {
            __builtin_amdgcn_global_load_lds(
                (const __attribute__((address_space(1))) void*)(gB + (size_t)i * 8 * DD + kk),
                (__attribute__((address_space(3))) void*)(&ws2[(size_t)buf * 64 * 64 + (wv * 16 + i * 8) * 64]),
                16, 0, 0);
        }
    };
    auto COMPQ = [&](int buf) {
        #pragma unroll
        for (int s = 0; s < 2; s++) {
            const int ca = ((s * 4 + lq) ^ fx) * 8;
            bf16x8 a = *(const bf16x8*)&qs[(size_t)buf * TB2 * 64 + (wr + l15) * 64 + ca];
            #pragma unroll
            for (int ni = 0; ni < 2; ni++) {
                bf16x8 bb = *(const bf16x8*)&ws2[(size_t)buf * 64 * 64 + (wc + ni * 16 + l15) * 64 + ca];
                acc[ni] = __builtin_amdgcn_mfma_f32_16x16x32_bf16(a, bb, acc[ni], 0, 0, 0);
            }
        }
    };

    int cur = 0;
    STAGEQ(0, 0);
    __syncthreads();
    for (int t = 0; t < 16; ++t) {
        const bool more = (t + 1 < 16);
        if (more) STAGEQ(cur ^ 1, (t + 1) * 64);
        COMPQ(cur);
        if (more) __syncthreads();
        cur ^= 1;
    }
    // write frags to Ls: row = wr + lq*4 + r, col = wc + ni*16 + l15
    #pragma unroll
    for (int ni = 0; ni < 2; ni++)
        #pragma unroll
        for (int r = 0; r < 4; r++)
            Ls[wr + lq * 4 + r][wc + ni * 16 + l15] = acc[ni][r];
    __syncthreads();

    // ---- softmax over cols 0..20 (scale0) and 21..61 (scale1) -> cw ----
    if (tid < TB2) {
        float s0 = scale_w[0], s1 = scale_w[1];
        float mm = fmaxf(s0, s1);
        float e0 = __expf(s0 - mm), e1 = __expf(s1 - mm);
        float inv01 = 1.0f / (e0 + e1);
        float sw0 = e0 * inv01, sw1 = e1 * inv01;

        float w0[C0], w1[C1];
        {
            float m = -1e30f;
            #pragma unroll
            for (int j = 0; j < C0; j++) { w0[j] = Ls[tid][j]; m = fmaxf(m, w0[j]); }
            float s = 0.0f;
            #pragma unroll
            for (int j = 0; j < C0; j++) { w0[j] = __expf(w0[j] - m); s += w0[j]; }
            float inv = sw0 / s;
            #pragma unroll
            for (int j = 0; j < C0; j++) w0[j] *= inv;
        }
        {
            float m = -1e30f;
            #pragma unroll
            for (int j = 0; j < C1; j++) { w1[j] = Ls[tid][C0 + j]; m = fmaxf(m, w1[j]); }
            float s = 0.0f;
            #pragma unroll
            for (int j = 0; j < C1; j++) { w1[j] = __expf(w1[j] - m); s += w1[j]; }
            float inv = sw1 / s;
            #pragma unroll
            for (int j = 0; j < C1; j++) w1[j] *= inv;
        }
        #pragma unroll
        for (int o = 0; o < C1; o++) {
            float w = w1[o];
            if (o >= 10 && o <= 30) w += w0[o - 10];
            cw[tid][o] = w;
        }
    }
    __syncthreads();

    // ---- window sum ----
    const int tq = tid >> 6;
    const int dg = tid & 63;
    const int d  = dg * 4;

    for (int tloc = 0; tloc < 8; tloc++) {
        const int tp = tq * 8 + tloc;
        f32x4 o4acc = {0.f, 0.f, 0.f, 0.f};
        #pragma unroll
        for (int o = 0; o < C1; o++) {
            float w = cw[tp][o];
            ushort4 vv = *(const ushort4*)(&vs[tp + o][d]);
            o4acc[0] = fmaf(w, bf2f(vv.x), o4acc[0]);
            o4acc[1] = fmaf(w, bf2f(vv.y), o4acc[1]);
            o4acc[2] = fmaf(w, bf2f(vv.z), o4acc[2]);
            o4acc[3] = fmaf(w, bf2f(vv.w), o4acc[3]);
        }
        const int bt = bt0 + tp;
        ushort4 o4;
        o4.x = f2bf(o4acc[0]); o4.y = f2bf(o4acc[1]);
        o4.z = f2bf(o4acc[2]); o4.w = f2bf(o4acc[3]);
        *(ushort4*)(x + (size_t)bt * DD + h * 256 + d) = o4;
    }
}

// ---------------------------------- launch ----------------------------------
extern "C" void kernel_launch(void* const* d_in, const int* in_sizes, int n_in,
                              void* d_out, int out_size, void* d_ws, size_t ws_size,
                              hipStream_t stream)
{
    const float* query   = (const float*)d_in[0];
    const float* W_qv    = (const float*)d_in[3];
    const float* W2_0    = (const float*)d_in[4];
    const float* W2_1    = (const float*)d_in[5];
    const float* scale_w = (const float*)d_in[6];
    const float* W_out   = (const float*)d_in[7];
    float* out = (float*)d_out;

    // Workspace layout (logitsP eliminated by the attn fusion)
    char* ws = (char*)d_ws;
    ushort* W2Tph    = (ushort*)ws;                 ws += (size_t)4 * 64 * DD * 2;      // 0.5 MB
    ushort* WoutT    = (ushort*)ws;                 ws += (size_t)DD * DD * 2;          // 2 MB
    ushort* query_bf = (ushort*)ws;                 ws += (size_t)BT * DD * 2;          // 8 MB
    ushort* WqvT     = (ushort*)ws;                 ws += (size_t)2 * DD * DD * 2;      // 4 MB
    ushort* reluq    = (ushort*)ws;                 ws += (size_t)BT * DD * 2;          // 8 MB
    ushort* vbuf     = (ushort*)ws;                 ws += (size_t)BT * DD * 2;          // 8 MB
    ushort* xbuf     = (ushort*)ws;                 ws += (size_t)BT * DD * 2;          // 8 MB

    // 0) all conversions in one launch
    convert_all<<<R4, 256, 0, stream>>>(query, query_bf, W_qv, WqvT,
                                        W_out, WoutT, W2_0, W2_1, W2Tph);

    // 1) qv GEMM: [4096,1024]x[1024,2048] -> reluq + vbuf (512 blocks x 512 thr)
    {   dim3 grid(2 * DD / 128, BT / 128, 1);
        gemm_mfma<128><<<grid, 512, 0, stream>>>(query_bf, WqvT, DD, DD,
                                                 nullptr, reluq, vbuf, 2, 0); }
    // 2) fused logits + softmax + sliding window -> xbuf (512 blocks)
    attn_fused_kernel<<<512, 256, LDS_TOTAL, stream>>>(reluq, W2Tph, vbuf,
                                                       scale_w, xbuf);

    // 3) out GEMM: x x WoutT -> out f32 (512 blocks)
    {   dim3 grid(DD / 64, BT / 128, 1);
        gemm_mfma<64><<<grid, 512, 0, stream>>>(xbuf, WoutT, DD, DD,
                                                out, nullptr, nullptr, 0, DD); }
}